// Round 5
// baseline (186.307 us; speedup 1.0000x reference)
//
#include <hip/hip_runtime.h>
#include <hip/hip_bf16.h>
#include <cstdint>
#include <cstddef>

typedef __attribute__((ext_vector_type(4))) float f32x4;
typedef __attribute__((ext_vector_type(8))) short s16x8;
typedef __attribute__((ext_vector_type(4))) unsigned short u16x4;
typedef __attribute__((ext_vector_type(8))) unsigned short u16x8;

#define NB 32
#define DD 512
#define TT 4096
#define HH 512
#define TB 64     // t-tile per block
#define BK 64     // k per iteration
#define NKK 8     // 512/BK

__device__ __forceinline__ unsigned short f2bf(float f) {
  uint32_t u = __builtin_bit_cast(uint32_t, f);
  u += 0x7fffu + ((u >> 16) & 1u);   // RNE
  return (unsigned short)(u >> 16);
}

__device__ __forceinline__ float tanh_fast(float x) {
  x = fminf(fmaxf(x, -15.f), 15.f);
  float e = __expf(2.f * x);
  return (e - 1.f) / (e + 1.f);
}

// --- A1: W1swz[kk32][s][h] : 16B chunk = W1[h][kk32*32 + s*8 .. +7] in bf16 ---
__global__ void kConvT(const float* __restrict__ w42, u16x8* __restrict__ W1swz) {
  int g = blockIdx.x * 256 + threadIdx.x;
  int h = g & 511, sk = g >> 9;
  int kk = sk >> 2, s = sk & 3;
  const float* src = &w42[h * 1024 + kk * 32 + s * 8];
  f32x4 v0 = *reinterpret_cast<const f32x4*>(src);
  f32x4 v1 = *reinterpret_cast<const f32x4*>(src + 4);
  u16x8 c;
  c[0] = f2bf(v0.x); c[1] = f2bf(v0.y); c[2] = f2bf(v0.z); c[3] = f2bf(v0.w);
  c[4] = f2bf(v1.x); c[5] = f2bf(v1.y); c[6] = f2bf(v1.z); c[7] = f2bf(v1.w);
  W1swz[kk * 2048 + s * 512 + h] = c;
}

// --- A2: qterm[b,h] = w42[h,512:]·query[b] + b4[h] ---
__global__ void kQterm(const float* __restrict__ w42, const float* __restrict__ query,
                       const float* __restrict__ b4, float* __restrict__ qterm) {
  int wid = blockIdx.x * 4 + (threadIdx.x >> 6);
  int lane = threadIdx.x & 63;
  int b = wid >> 9, h = wid & 511;
  const float* wr = &w42[h * 1024 + 512];
  const float* q  = &query[b * 512];
  int d = lane * 8;
  f32x4 w0 = *(const f32x4*)&wr[d], w1 = *(const f32x4*)&wr[d + 4];
  f32x4 q0 = *(const f32x4*)&q[d],  q1 = *(const f32x4*)&q[d + 4];
  float s = w0.x*q0.x + w0.y*q0.y + w0.z*q0.z + w0.w*q0.w
          + w1.x*q1.x + w1.y*q1.y + w1.z*q1.z + w1.w*q1.w;
  #pragma unroll
  for (int off = 32; off; off >>= 1) s += __shfl_xor(s, off);
  if (lane == 0) qterm[b * 512 + h] = s + b4[h];
}

// --- B: GEMM + tanh + h-reduce + exp.  BK=64, nt keys loads.
__global__ __launch_bounds__(256, 2) void kGemmE(
    const float* __restrict__ keys, const u16x8* __restrict__ W1swz,
    const float* __restrict__ qterm, const float* __restrict__ w54,
    float* __restrict__ e, float* __restrict__ Zp) {
  __shared__ s16x8 Bs[2][8][64];   // 16 KB: [buf][slot k/8][t]
  __shared__ float red[4][64];

  int bid = blockIdx.x;
  int b = bid >> 6, tblk = bid & 63;
  int t0 = tblk * TB;
  int tid = threadIdx.x, lane = tid & 63, w = tid >> 6;
  int lr = lane & 15, lg = lane >> 4;

  // wave w stages k-rows w*16 .. w*16+15 (slots 2w, 2w+1)
  const float* kp = keys + (size_t)b * DD * TT + (size_t)(w * 16) * TT + t0 + lane;
  const s16x8* ap = reinterpret_cast<const s16x8*>(W1swz) + lg * 512 + w * 128 + lr;

  f32x4 acc[8][4];
  #pragma unroll
  for (int m = 0; m < 8; ++m)
    #pragma unroll
    for (int n = 0; n < 4; ++n) acc[m][n] = (f32x4){0.f, 0.f, 0.f, 0.f};

  float r[2][16];
  #pragma unroll
  for (int j = 0; j < 16; ++j) r[0][j] = __builtin_nontemporal_load(&kp[(size_t)j * TT]);
  #pragma unroll
  for (int j = 0; j < 16; ++j) r[1][j] = __builtin_nontemporal_load(&kp[(size_t)(BK + j) * TT]);

  #pragma unroll
  for (int kk = 0; kk < NKK; ++kk) {
    const int cur = kk & 1;
    // A-frags for this step (L2; issued first, consumed after barrier+convert)
    s16x8 af[16];
    #pragma unroll
    for (int ss = 0; ss < 2; ++ss)
      #pragma unroll
      for (int m = 0; m < 8; ++m)
        af[ss * 8 + m] = ap[(2 * kk + ss) * 2048 + m * 16];

    // convert this step's B regs -> two bf16 chunks -> LDS
    s16x8 c0, c1;
    #pragma unroll
    for (int j = 0; j < 8; ++j) { c0[j] = (short)f2bf(r[cur][j]); c1[j] = (short)f2bf(r[cur][8 + j]); }
    Bs[cur][2 * w][lane] = c0;
    Bs[cur][2 * w + 1][lane] = c1;

    // depth-2 B prefetch (HBM, non-temporal)
    if (kk + 2 < NKK) {
      const float* kp2 = kp + (size_t)(kk + 2) * BK * TT;
      #pragma unroll
      for (int j = 0; j < 16; ++j) r[cur][j] = __builtin_nontemporal_load(&kp2[(size_t)j * TT]);
    }

    asm volatile("s_waitcnt lgkmcnt(0)" ::: "memory");
    __builtin_amdgcn_s_barrier();

    s16x8 bf[2][4];
    #pragma unroll
    for (int ss = 0; ss < 2; ++ss)
      #pragma unroll
      for (int n = 0; n < 4; ++n)
        bf[ss][n] = Bs[cur][ss * 4 + lg][n * 16 + lr];

    #pragma unroll
    for (int ss = 0; ss < 2; ++ss)
      #pragma unroll
      for (int m = 0; m < 8; ++m)
        #pragma unroll
        for (int n = 0; n < 4; ++n)
          acc[m][n] = __builtin_amdgcn_mfma_f32_16x16x32_bf16(af[ss * 8 + m], bf[ss][n], acc[m][n], 0, 0, 0);
  }

  // epilogue: tanh + w54-weighted reduce over this wave's 128 h
  float part[4] = {0.f, 0.f, 0.f, 0.f};
  int hb = w * 128;
  #pragma unroll
  for (int m = 0; m < 8; ++m) {
    #pragma unroll
    for (int rr = 0; rr < 4; ++rr) {
      int h = hb + m * 16 + lg * 4 + rr;     // C/D: row=(lane>>4)*4+reg
      float qv = qterm[b * HH + h];
      float wv = w54[h];
      #pragma unroll
      for (int n = 0; n < 4; ++n)
        part[n] += wv * tanh_fast(acc[m][n][rr] + qv);
    }
  }
  #pragma unroll
  for (int n = 0; n < 4; ++n) {
    part[n] += __shfl_xor(part[n], 16);
    part[n] += __shfl_xor(part[n], 32);
  }
  if (lane < 16) {
    #pragma unroll
    for (int n = 0; n < 4; ++n) red[w][n * 16 + lane] = part[n];
  }
  __syncthreads();
  if (tid < 64) {
    float v = red[0][tid] + red[1][tid] + red[2][tid] + red[3][tid];
    float ev = __expf(v);                    // |n5| <~ 4: no max-sub needed
    e[b * TT + t0 + tid] = ev;
    float z = ev;
    #pragma unroll
    for (int off = 32; off; off >>= 1) z += __shfl_xor(z, off);
    if (tid == 0) Zp[b * 64 + tblk] = z;
  }
}

// --- C: Zinv[b] = 1 / sum_tiles Zp[b][tile] ---
__global__ void kZinv(const float* __restrict__ Zp, float* __restrict__ Zinv) {
  int b = blockIdx.x, lane = threadIdx.x;
  float z = Zp[b * 64 + lane];
  #pragma unroll
  for (int off = 32; off; off >>= 1) z += __shfl_xor(z, off);
  if (lane == 0) Zinv[b] = 1.f / z;
}

// --- D: out[b,v] = Zinv[b] * values[b,v,:]·e[b,:]  (nt values, 4-way ILP) ---
__global__ void kOut(const float* __restrict__ values, const float* __restrict__ e,
                     const float* __restrict__ Zinv, float* __restrict__ out) {
  int blk = blockIdx.x;
  int b = blk >> 7;
  int wid = threadIdx.x >> 6, lane = threadIdx.x & 63;
  int v = (blk & 127) * 4 + wid;
  const float* row = &values[((size_t)b * 512 + v) * TT];
  const float* wv = &e[b * TT];
  float s0 = 0.f, s1 = 0.f, s2 = 0.f, s3 = 0.f;
  #pragma unroll
  for (int i = 0; i < 16; ++i) {
    int t = (i * 64 + lane) * 4;
    f32x4 x = __builtin_nontemporal_load(reinterpret_cast<const f32x4*>(&row[t]));
    f32x4 y = *(const f32x4*)&wv[t];
    float d = x.x * y.x + x.y * y.y + x.z * y.z + x.w * y.w;
    if ((i & 3) == 0) s0 += d; else if ((i & 3) == 1) s1 += d;
    else if ((i & 3) == 2) s2 += d; else s3 += d;
  }
  float s = (s0 + s1) + (s2 + s3);
  #pragma unroll
  for (int off = 32; off; off >>= 1) s += __shfl_xor(s, off);
  if (lane == 0) out[b * 512 + v] = s * Zinv[b];
}

extern "C" void kernel_launch(void* const* d_in, const int* in_sizes, int n_in,
                              void* d_out, int out_size, void* d_ws, size_t ws_size,
                              hipStream_t stream) {
  const float* query  = (const float*)d_in[0];
  const float* keys   = (const float*)d_in[1];
  const float* values = (const float*)d_in[2];
  const float* w42    = (const float*)d_in[3];
  const float* b4     = (const float*)d_in[4];
  const float* w54    = (const float*)d_in[5];
  // d_in[6] (b5) shifts n5 by a constant -> softmax-invariant; unused.
  float* out = (float*)d_out;

  char* ws = (char*)d_ws;
  u16x8* W1swz = (u16x8*)ws;                       // 512 KB
  float* qterm = (float*)(ws + (512 << 10));       // 64 KB
  float* Zp    = (float*)(ws + (576 << 10));       // 8 KB   [B][64]
  float* Zinv  = (float*)(ws + (592 << 10));       // 128 B
  float* e     = (float*)(ws + (640 << 10));       // 512 KB [B][T]

  kConvT <<<128, 256, 0, stream>>>(w42, W1swz);
  kQterm <<<4096, 256, 0, stream>>>(w42, query, b4, qterm);
  kGemmE <<<2048, 256, 0, stream>>>(keys, W1swz, qterm, w54, e, Zp);
  kZinv  <<<32, 64, 0, stream>>>(Zp, Zinv);
  kOut   <<<4096, 256, 0, stream>>>(values, e, Zinv, out);
}